// Round 5
// baseline (379.670 us; speedup 1.0000x reference)
//
#include <hip/hip_runtime.h>
#include <hip/hip_bf16.h>
#include <cstdint>

// Problem sizes (fixed by reference setup_inputs)
#define B_SZ 8192
#define F_SZ 4096
#define D_SZ 1024
#define K_SZ 2048  // 2*D : A = [x^2 | x], W = [inv2 | -2*mu*inv2]

typedef __bf16 bf16x8 __attribute__((ext_vector_type(8)));
typedef float f32x4 __attribute__((ext_vector_type(4)));
typedef float fvec4 __attribute__((ext_vector_type(4)));
typedef unsigned short u16x4 __attribute__((ext_vector_type(4)));

// round-to-nearest-even fp32 -> bf16 bits
__device__ __forceinline__ unsigned short f2bf(float f) {
    union { float f; unsigned u; } c; c.f = f;
    unsigned r = c.u + 0x7fff + ((c.u >> 16) & 1);
    return (unsigned short)(r >> 16);
}

// async global->LDS, 16 B per lane; LDS dest = wave-uniform base + lane*16
__device__ __forceinline__ void async16(const void* g, void* l) {
    __builtin_amdgcn_global_load_lds(
        (__attribute__((address_space(1))) void*)g,
        (__attribute__((address_space(3))) void*)l, 16, 0, 0);
}

// ---------------- prep (unchanged from r4: measured fine) ----------------
__global__ __launch_bounds__(256) void prep(const float* __restrict__ x,
                                            const float* __restrict__ mu,
                                            const float* __restrict__ sd,
                                            unsigned short* __restrict__ A,
                                            unsigned short* __restrict__ W,
                                            float* __restrict__ nmm) {
    const int tid = threadIdx.x;
    if (blockIdx.x < 4096) {
        const size_t o0 = (size_t)blockIdx.x * 2048 + tid * 4;
        fvec4 v0 = *(const fvec4*)(x + o0);
        fvec4 v1 = *(const fvec4*)(x + o0 + 1024);
        #pragma unroll
        for (int h = 0; h < 2; ++h) {
            fvec4 v = h ? v1 : v0;
            size_t oo = o0 + h * 1024;
            size_t b = oo >> 10;
            int d = (int)(oo & 1023);
            u16x4 xx, xs;
            xx.x = f2bf(v.x * v.x); xx.y = f2bf(v.y * v.y);
            xx.z = f2bf(v.z * v.z); xx.w = f2bf(v.w * v.w);
            xs.x = f2bf(v.x); xs.y = f2bf(v.y);
            xs.z = f2bf(v.z); xs.w = f2bf(v.w);
            *(u16x4*)(A + b * K_SZ + d) = xx;
            *(u16x4*)(A + b * K_SZ + 1024 + d) = xs;
        }
    } else {
        const int f = blockIdx.x - 4096;
        const int d = tid * 4;
        size_t off = (size_t)f * D_SZ + d;
        fvec4 m = *(const fvec4*)(mu + off);
        fvec4 s = *(const fvec4*)(sd + off);
        float i0 = 1.0f / (s.x * s.x), i1 = 1.0f / (s.y * s.y);
        float i2 = 1.0f / (s.z * s.z), i3 = 1.0f / (s.w * s.w);
        u16x4 wi, wm;
        wi.x = f2bf(i0); wi.y = f2bf(i1); wi.z = f2bf(i2); wi.w = f2bf(i3);
        wm.x = f2bf(-2.0f * m.x * i0); wm.y = f2bf(-2.0f * m.y * i1);
        wm.z = f2bf(-2.0f * m.z * i2); wm.w = f2bf(-2.0f * m.w * i3);
        size_t wb = (size_t)f * K_SZ + d;
        *(u16x4*)(W + wb) = wi;
        *(u16x4*)(W + wb + 1024) = wm;
        float mm = m.x * m.x * i0 + m.y * m.y * i1 + m.z * m.z * i2 + m.w * m.w * i3;
        #pragma unroll
        for (int o = 32; o > 0; o >>= 1) mm += __shfl_down(mm, o, 64);
        __shared__ float red[4];
        if ((tid & 63) == 0) red[tid >> 6] = mm;
        __syncthreads();
        if (tid == 0) nmm[f] = -0.5f * (red[0] + red[1] + red[2] + red[3]);
    }
}

// ---------------- producer-consumer GEMM ----------------
// out[b,f] = -0.5 * (A @ W^T)[b,f] + nmm[f]
// 128x128 tile, BK=32. 6 waves: waves 0-3 = consumers (64x64 each, 4x4
// 16x16x32 bf16 MFMA frags), wave 4 = A-producer, wave 5 = W-producer.
// 4-stage LDS ring (16 KB/stage), 3-stage issue-ahead. Consumers never have
// outstanding vmcnt -> no barrier drain; producers drain with fine-grained
// vmcnt(16) hidden inside inline asm (with the flag ds_write) so the
// compiler's waitcnt pass cannot force vmcnt(0).
// LDS tile layout: [128 rows][32 k] with XOR chunk swizzle: 16B chunk c of
// row r lives at slot c ^ ((r>>1)&3). Swizzle is applied on the GLOBAL
// source address (the LDS side of global_load_lds is fixed base+lane*16).
// This makes consumer ds_read_b128 exactly 2-way bank aliasing = free (m136).
#define STAGES 4
__global__ __launch_bounds__(384) void gemm_pc(const unsigned short* __restrict__ A,
                                               const unsigned short* __restrict__ W,
                                               const float* __restrict__ nmm,
                                               float* __restrict__ out) {
    __shared__ __align__(16) unsigned short ring[STAGES][2][128 * 32];
    __shared__ int flagA[STAGES];   // monotonic: stage s filled through iter flagA[s]
    __shared__ int flagB[STAGES];
    __shared__ int consd[STAGES];   // consume credits: +1 per consumer wave per instance

    const int tid  = threadIdx.x;
    const int wave = tid >> 6;
    const int lane = tid & 63;
    const int tileM = blockIdx.y * 128;
    const int tileN = blockIdx.x * 128;

    if (tid < STAGES) { flagA[tid] = 0; flagB[tid] = 0; consd[tid] = 0; }
    __syncthreads();

    if (wave >= 4) {
        // ---------------- producer ----------------
        const int part = wave - 4;                       // 0 = A, 1 = W
        const unsigned short* src =
            part == 0 ? A + (size_t)tileM * K_SZ : W + (size_t)tileN * K_SZ;
        int* flg = part == 0 ? flagA : flagB;
        const int lrow = lane >> 2;                       // 0..15 within 16-row group
        const int cswz = (lane & 3) ^ ((lane >> 3) & 3);  // global chunk for this slot
        const size_t laneoff = (size_t)lrow * K_SZ + cswz * 8;

        // issue stage j: 8 x async16 = 128 rows x 32 k
        auto issue = [&](int j) {
            const int s = j & (STAGES - 1);
            unsigned short* dst = &ring[s][part][0];
            const size_t k0 = (size_t)j * 32;
            #pragma unroll
            for (int q = 0; q < 8; ++q)
                async16(src + (size_t)q * 16 * K_SZ + laneoff + k0, dst + q * 512);
        };
        // signal: drain to `pend` outstanding loads, then ds_write flag = val.
        // Both inside one asm block: opaque to SIInsertWaitcnts.
        auto signal = [&](int s, int val, int pend) {
            unsigned faddr = (unsigned)(uintptr_t)(&flg[s]);
            if (pend == 16)
                asm volatile("s_waitcnt vmcnt(16)\n\tds_write_b32 %0, %1\n"
                             :: "v"(faddr), "v"(val) : "memory");
            else if (pend == 8)
                asm volatile("s_waitcnt vmcnt(8)\n\tds_write_b32 %0, %1\n"
                             :: "v"(faddr), "v"(val) : "memory");
            else
                asm volatile("s_waitcnt vmcnt(0)\n\tds_write_b32 %0, %1\n"
                             :: "v"(faddr), "v"(val) : "memory");
        };

        issue(0); issue(1); issue(2);                     // preload 3 stages
        for (int i = 0; i <= 61; ++i) {
            signal(i & (STAGES - 1), i + 1, 16);          // stage i done, 2 ahead in flight
            const int j = i + 3;
            if (j < 64) {
                const int s = j & (STAGES - 1), w = j >> 2;
                while (((volatile int*)consd)[s] < 4 * w) {}   // wait instance w-1 consumed
                asm volatile("" ::: "memory");
                issue(j);
            }
        }
        signal(62 & 3, 63, 8);
        signal(63 & 3, 64, 0);
        return;                                           // producers exit; no more barriers
    }

    // ---------------- consumer ----------------
    const int wm = (wave >> 1) * 64;
    const int wn = (wave & 1) * 64;
    const int r16  = lane & 15;
    const int quad = lane >> 4;
    const int swz  = (r16 >> 1) & 3;                      // read-side chunk swizzle

    const f32x4 vzero = {0.f, 0.f, 0.f, 0.f};
    f32x4 acc[4][4];
    #pragma unroll
    for (int i = 0; i < 4; ++i)
        #pragma unroll
        for (int j = 0; j < 4; ++j) acc[i][j] = vzero;

    for (int it = 0; it < 64; ++it) {
        const int s = it & (STAGES - 1);
        while (((volatile int*)flagA)[s] < it + 1 ||
               ((volatile int*)flagB)[s] < it + 1) {}
        asm volatile("" ::: "memory");                    // no hoisting reads above poll

        const unsigned short* tA = &ring[s][0][0];
        const unsigned short* tB = &ring[s][1][0];
        bf16x8 af[4], bfr[4];
        #pragma unroll
        for (int i = 0; i < 4; ++i)
            af[i] = *(const bf16x8*)(tA + (wm + i * 16 + r16) * 32 + (quad ^ swz) * 8);
        #pragma unroll
        for (int j = 0; j < 4; ++j)
            bfr[j] = *(const bf16x8*)(tB + (wn + j * 16 + r16) * 32 + (quad ^ swz) * 8);
        #pragma unroll
        for (int i = 0; i < 4; ++i)
            #pragma unroll
            for (int j = 0; j < 4; ++j)
                acc[i][j] = __builtin_amdgcn_mfma_f32_16x16x32_bf16(
                    af[i], bfr[j], acc[i][j], 0, 0, 0);

        asm volatile("" ::: "memory");                    // credit after the reads
        if (lane == 0) atomicAdd(&consd[s], 1);
    }

    // epilogue: C/D layout col=lane&15, row=quad*4+reg
    int   fc[4];
    float cj[4];
    #pragma unroll
    for (int j = 0; j < 4; ++j) {
        fc[j] = tileN + wn + j * 16 + r16;
        cj[j] = nmm[fc[j]];
    }
    #pragma unroll
    for (int i = 0; i < 4; ++i) {
        int mbase = tileM + wm + i * 16 + quad * 4;
        #pragma unroll
        for (int r = 0; r < 4; ++r) {
            float* orow = out + (size_t)(mbase + r) * F_SZ;
            #pragma unroll
            for (int j = 0; j < 4; ++j)
                orow[fc[j]] = -0.5f * acc[i][j][r] + cj[j];
        }
    }
}

extern "C" void kernel_launch(void* const* d_in, const int* in_sizes, int n_in,
                              void* d_out, int out_size, void* d_ws, size_t ws_size,
                              hipStream_t stream) {
    const float* x  = (const float*)d_in[0];
    const float* mu = (const float*)d_in[1];
    const float* sd = (const float*)d_in[2];
    float* out = (float*)d_out;

    // workspace: A (8192x2048 bf16, 33.5 MB) | W (4096x2048 bf16, 16.8 MB) | nmm (16 KB)
    unsigned short* A = (unsigned short*)d_ws;
    unsigned short* W = A + (size_t)B_SZ * K_SZ;
    float* nmm = (float*)(W + (size_t)F_SZ * K_SZ);

    prep<<<8192, 256, 0, stream>>>(x, mu, sd, A, W, nmm);
    gemm_pc<<<dim3(F_SZ / 128, B_SZ / 128), 384, 0, stream>>>(A, W, nmm, out);
}